// Round 12
// baseline (606.443 us; speedup 1.0000x reference)
//
#include <hip/hip_runtime.h>
#include <hip/hip_bf16.h>
#include <math.h>

#define H 512
#define V 128
#define NLEAF 16384

typedef __attribute__((ext_vector_type(4))) float f32x4;
typedef __attribute__((ext_vector_type(8))) short s16x8;
typedef __attribute__((ext_vector_type(4))) unsigned short u16x4;
typedef unsigned short ushort_t;

// ---- static device scratch ----
__device__ ushort_t g_hb0[NLEAF * H];        // h bf16 (levels 12,10,...,0)
__device__ ushort_t g_hb1[(NLEAF / 2) * H];  // h bf16 (levels 13,11,...,1)
__device__ float    g_c0[NLEAF * H];         // c f32
__device__ float    g_c1[(NLEAF / 2) * H];
__device__ __align__(16) ushort_t g_htab[V * H];  // leaf h by token
__device__ __align__(16) float    g_ctab[V * H];  // leaf c by token
__device__ __align__(16) float    g_Wpack[V * H * 4]; // {Wi+b,Wo+b,Wu+b,Wf+bf}
__device__ __align__(16) float    g_Uh0[V * 3 * H];  // htab . Uiou[k<512]
__device__ __align__(16) float    g_Uh1[V * 3 * H];  // htab . Uiou[k>=512]
__device__ __align__(16) float    g_Vf0[V * H];      // htab . Uf0
__device__ __align__(16) float    g_Vf1[V * H];      // htab . Uf1
__device__ ushort_t g_UiouT[3 * H * 2 * H];  // [1536 cols][1024 k] bf16
__device__ ushort_t g_UfT[H * 2 * H];        // [512 cols][1024 k] bf16
__device__ ushort_t g_UiouTt[3 * H * 3 * H]; // root
__device__ ushort_t g_UfTt[H * 3 * H];       // root f
__device__ float    g_rpart[3 * 3072];
__device__ float    g_hf[H];
__device__ float    g_gates[4 * H];

__device__ __forceinline__ float sigm(float x) { return 1.0f / (1.0f + __expf(-x)); }
__device__ __forceinline__ float ftanh(float x) {
  return 1.0f - 2.0f / (__expf(2.0f * x) + 1.0f);
}
__device__ __forceinline__ ushort_t f2bf(float x) {
  __hip_bfloat16 b = __float2bfloat16(x);
  return *reinterpret_cast<ushort_t*>(&b);
}
__device__ __forceinline__ float bf2f(ushort_t u) {
  union { unsigned int i; float f; } v; v.i = ((unsigned int)u) << 16; return v.f;
}
__device__ __forceinline__ void gload_lds16(const void* g, void* l) {
  __builtin_amdgcn_global_load_lds(
      (const __attribute__((address_space(1))) unsigned int*)g,
      (__attribute__((address_space(3))) unsigned int*)l, 16, 0, 0);
}

// ------ prep: 4 weight transposes (z<4) + Wpack/leaf tables (z==4) ---------
__global__ __launch_bounds__(256) void k_prep(
    const float* __restrict__ s0, const float* __restrict__ s1,
    const float* __restrict__ s2, const float* __restrict__ s3,
    ushort_t* __restrict__ d0, ushort_t* __restrict__ d1,
    ushort_t* __restrict__ d2, ushort_t* __restrict__ d3,
    const float* __restrict__ Wiou, const float* __restrict__ biou,
    const float* __restrict__ Wf, const float* __restrict__ bf) {
  if (blockIdx.z == 4) {                     // Wpack + leaf (h,c) tables
    const int v = blockIdx.y * 48 + blockIdx.x;
    if (v >= V) return;
    for (int j = threadIdx.x; j < H; j += 256) {
      float wi = Wiou[(size_t)v * 1536 + j] + biou[j];
      float wo = Wiou[(size_t)v * 1536 + 512 + j] + biou[512 + j];
      float wu = Wiou[(size_t)v * 1536 + 1024 + j] + biou[1024 + j];
      float wf = Wf[(size_t)v * 512 + j] + bf[j];
      f32x4 wp = {wi, wo, wu, wf};
      *reinterpret_cast<f32x4*>(&g_Wpack[((size_t)v * 512 + j) * 4]) = wp;
      float c = sigm(wi) * ftanh(wu);
      float h = sigm(wo) * ftanh(c);
      g_htab[v * H + j] = f2bf(h);
      g_ctab[v * H + j] = c;
    }
    return;
  }
  const float* src; ushort_t* dst; int R, Cc;
  switch (blockIdx.z) {
    case 0: src = s0; dst = d0; R = 1024; Cc = 1536; break;
    case 1: src = s1; dst = d1; R = 1024; Cc = 512; break;
    case 2: src = s2; dst = d2; R = 1536; Cc = 1536; break;
    default: src = s3; dst = d3; R = 1536; Cc = 512; break;
  }
  int bc = blockIdx.x * 32, br = blockIdx.y * 32;
  if (bc >= Cc || br >= R) return;
  __shared__ float t[32][33];
  int tx = threadIdx.x & 31, ty = threadIdx.x >> 5;
  for (int rr = ty; rr < 32; rr += 8)
    t[rr][tx] = src[(size_t)(br + rr) * Cc + bc + tx];
  __syncthreads();
  for (int rr = ty; rr < 32; rr += 8)
    dst[(size_t)(bc + rr) * R + br + tx] = f2bf(t[tx][rr]);
}

// ------ Uh tables: per token v, dot htab[v] with U columns (k-halves) ------
// grid (128 v, 16 chunks), 256 thr; unit c: [0,1536) Uh0, [1536,3072) Uh1,
// [3072,3584) Vf0, [3584,4096) Vf1.
__global__ __launch_bounds__(256) void k_uh() {
  const int v = blockIdx.x;
  const int c = blockIdx.y * 256 + threadIdx.x;
  __shared__ float hl[512];
  for (int t = threadIdx.x; t < 512; t += 256) hl[t] = bf2f(g_htab[v * 512 + t]);
  __syncthreads();
  const ushort_t* col; float* dst;
  if (c < 1536)      { col = g_UiouT + (size_t)c * 1024;
                       dst = &g_Uh0[(size_t)v * 1536 + c]; }
  else if (c < 3072) { col = g_UiouT + (size_t)(c - 1536) * 1024 + 512;
                       dst = &g_Uh1[(size_t)v * 1536 + (c - 1536)]; }
  else if (c < 3584) { col = g_UfT + (size_t)(c - 3072) * 1024;
                       dst = &g_Vf0[(size_t)v * 512 + (c - 3072)]; }
  else               { col = g_UfT + (size_t)(c - 3584) * 1024 + 512;
                       dst = &g_Vf1[(size_t)v * 512 + (c - 3584)]; }
  float acc = 0.f;
  #pragma unroll 4
  for (int k0 = 0; k0 < 512; k0 += 8) {
    s16x8 wv = *(const s16x8*)(col + k0);
    #pragma unroll
    for (int r = 0; r < 8; ++r) acc += hl[k0 + r] * bf2f((ushort_t)wv[r]);
  }
  *dst = acc;
}

// ------ lvl 13 cell: pure gather+elementwise (children are leaves) ---------
__global__ __launch_bounds__(256) void k_top_cell(const int* __restrict__ tokens) {
  const int total = 8192 * 128;              // quads
  for (int q = blockIdx.x * 256 + threadIdx.x; q < total; q += gridDim.x * 256) {
    int i = q >> 7, jv = q & 127;
    int t0 = tokens[(NLEAF - 1) + 2 * i];
    int t1 = tokens[(NLEAF - 1) + 2 * i + 1];
    int tk = tokens[8191 + i];
    const f32x4* u0 = (const f32x4*)&g_Uh0[(size_t)t0 * 1536];
    const f32x4* u1 = (const f32x4*)&g_Uh1[(size_t)t1 * 1536];
    f32x4 ii = u0[jv] + u1[jv];
    f32x4 oo = u0[128 + jv] + u1[128 + jv];
    f32x4 uu = u0[256 + jv] + u1[256 + jv];
    f32x4 v0 = ((const f32x4*)&g_Vf0[(size_t)t0 * 512])[jv];
    f32x4 v1 = ((const f32x4*)&g_Vf1[(size_t)t1 * 512])[jv];
    f32x4 c0 = ((const f32x4*)&g_ctab[(size_t)t0 * 512])[jv];
    f32x4 c1 = ((const f32x4*)&g_ctab[(size_t)t1 * 512])[jv];
    const f32x4* wpp = (const f32x4*)g_Wpack + (size_t)tk * 512 + jv * 4;
    u16x4 hv; f32x4 cv;
    #pragma unroll
    for (int r = 0; r < 4; ++r) {
      f32x4 wp = wpp[r];
      float ig = ii[r] + wp[0];
      float og = oo[r] + wp[1];
      float ug = uu[r] + wp[2];
      float fp = wp[3];
      float cc = sigm(ig) * ftanh(ug) + sigm(fp + v0[r]) * c0[r]
               + sigm(fp + v1[r]) * c1[r];
      float hh = sigm(og) * ftanh(cc);
      cv[r] = cc;
      hv[r] = f2bf(hh);
    }
    *reinterpret_cast<u16x4*>(&g_hb1[(size_t)q * 4]) = hv;
    *reinterpret_cast<f32x4*>(&g_c1[(size_t)q * 4]) = cv;
  }
}

// ====== shared MFMA compute macro ======
#define MFMA_COMPUTE(FA)                                                     \
  {                                                                          \
    const char* ab = smem + buf * 8192 + wry * 4096 + lane * 16;             \
    s16x8 a0 = *(const s16x8*)(ab);                                          \
    s16x8 a1 = *(const s16x8*)(ab + 1024);                                   \
    s16x8 a2 = *(const s16x8*)(ab + 2048);                                   \
    s16x8 a3 = *(const s16x8*)(ab + 3072);                                   \
    const char* bb = smem + 24576 + buf * 16384 + cx * 2048 + lane * 16;     \
    s16x8 b0 = *(const s16x8*)(bb);                                          \
    s16x8 b1 = *(const s16x8*)(bb + 1024);                                   \
    s16x8 b2 = *(const s16x8*)(bb + 4096);                                   \
    s16x8 b3 = *(const s16x8*)(bb + 5120);                                   \
    s16x8 b4 = *(const s16x8*)(bb + 8192);                                   \
    s16x8 b5 = *(const s16x8*)(bb + 9216);                                   \
    s16x8 b6 = *(const s16x8*)(bb + 12288);                                  \
    s16x8 b7 = *(const s16x8*)(bb + 13312);                                  \
    s16x8 aa[4] = {a0, a1, a2, a3};                                          \
    _Pragma("unroll")                                                        \
    for (int rtl = 0; rtl < 4; ++rtl) {                                      \
      acc[rtl][0] = __builtin_amdgcn_mfma_f32_16x16x32_bf16(aa[rtl], b0, acc[rtl][0], 0, 0, 0); \
      acc[rtl][1] = __builtin_amdgcn_mfma_f32_16x16x32_bf16(aa[rtl], b1, acc[rtl][1], 0, 0, 0); \
      acc[rtl][2] = __builtin_amdgcn_mfma_f32_16x16x32_bf16(aa[rtl], b2, acc[rtl][2], 0, 0, 0); \
      acc[rtl][3] = __builtin_amdgcn_mfma_f32_16x16x32_bf16(aa[rtl], b3, acc[rtl][3], 0, 0, 0); \
      acc[rtl][4] = __builtin_amdgcn_mfma_f32_16x16x32_bf16(aa[rtl], b4, acc[rtl][4], 0, 0, 0); \
      acc[rtl][5] = __builtin_amdgcn_mfma_f32_16x16x32_bf16(aa[rtl], b5, acc[rtl][5], 0, 0, 0); \
      acc[rtl][FA] = __builtin_amdgcn_mfma_f32_16x16x32_bf16(aa[rtl], b6, acc[rtl][FA], 0, 0, 0); \
      acc[rtl][FA + 1] = __builtin_amdgcn_mfma_f32_16x16x32_bf16(aa[rtl], b7, acc[rtl][FA + 1], 0, 0, 0); \
    }                                                                        \
  }
#define WAITV(N) asm volatile("s_waitcnt vmcnt(" #N ")" ::: "memory")

// ---------------- levels 12..8: depth-3, 72KB, Wpack epilogue --------------
__global__ __launch_bounds__(256, 2) void k_mfma_rest(int lvl,
    const int* __restrict__ tokens) {
  const int n = 1 << lvl;
  const int node0 = n - 1;
  const int outp = lvl & 1;
  const ushort_t* __restrict__ hprev = outp ? g_hb0 : g_hb1;
  const float* __restrict__ cprev = outp ? g_c0 : g_c1;
  ushort_t* __restrict__ hout = outp ? g_hb1 : g_hb0;
  float* __restrict__ cout = outp ? g_c1 : g_c0;

  const int i0 = blockIdx.x * 128;
  const int j0 = blockIdx.y * 64;
  const int tid = threadIdx.x;
  const int lane = tid & 63;
  const int w = tid >> 6;
  const int wry = w >> 1;
  const int cx = w & 1;

  __shared__ f32x4 smemv[4608];  // 72KB
  char* smem = (char*)smemv;

  const char* gp[6];
  unsigned lb[6], lstr[6];
  {
    int kb = (lane >> 4) * 16;
    #pragma unroll
    for (int q = 0; q < 6; ++q) {
      int c = w * 6 + q;
      if (c < 8) {
        int row = i0 + c * 16 + (lane & 15);
        gp[q] = (const char*)hprev + (size_t)row * 2048 + kb;
        lb[q] = c * 1024u;
        lstr[q] = 8192u;
      } else {
        int ct = c - 8;
        int col = ct * 16 + (lane & 15);
        int g = col >> 6, jj = j0 + (col & 63);
        const ushort_t* Ub = (g < 3) ? (g_UiouT + (size_t)(g * 512 + jj) * 1024)
                                     : (g_UfT + (size_t)jj * 1024);
        gp[q] = (const char*)Ub + kb;
        lb[q] = 24576u + ct * 1024u;
        lstr[q] = 16384u;
      }
    }
  }

#define STAGE_R(BUF)                                                 \
  {                                                                  \
    _Pragma("unroll")                                                \
    for (int q = 0; q < 6; ++q) {                                    \
      gload_lds16(gp[q], smem + lb[q] + (unsigned)(BUF) * lstr[q]);  \
      gp[q] += 64;                                                   \
    }                                                                \
  }

  f32x4 acc[4][10];
  #pragma unroll
  for (int a = 0; a < 4; ++a)
    #pragma unroll
    for (int b = 0; b < 10; ++b) acc[a][b] = (f32x4){0.f, 0.f, 0.f, 0.f};

  STAGE_R(0); STAGE_R(1); STAGE_R(2);
  int buf = 0;
  for (int kt = 0; kt < 16; ++kt) {
    WAITV(12);
    __builtin_amdgcn_s_barrier();
    MFMA_COMPUTE(6);
    __builtin_amdgcn_s_barrier();
    STAGE_R(buf);
    buf = (buf == 2) ? 0 : buf + 1;
  }
  for (int kt = 16; kt < 29; ++kt) {
    WAITV(12);
    __builtin_amdgcn_s_barrier();
    MFMA_COMPUTE(8);
    __builtin_amdgcn_s_barrier();
    STAGE_R(buf);
    buf = (buf == 2) ? 0 : buf + 1;
  }
  WAITV(12); __builtin_amdgcn_s_barrier(); MFMA_COMPUTE(8);
  buf = (buf == 2) ? 0 : buf + 1;
  WAITV(6);  __builtin_amdgcn_s_barrier(); MFMA_COMPUTE(8);
  buf = (buf == 2) ? 0 : buf + 1;
  WAITV(0);  __builtin_amdgcn_s_barrier(); MFMA_COMPUTE(8);
#undef STAGE_R

  // Wpack epilogue: one 16B read replaces 7 scattered 4B reads
  const int node_c = lane >> 4;
  const int jl = lane & 15;
  #pragma unroll
  for (int t = 0; t < 2; ++t) {
    const int j = j0 + cx * 32 + t * 16 + jl;
    #pragma unroll
    for (int rtl = 0; rtl < 4; ++rtl) {
      f32x4 vi = acc[rtl][0 + t], vo = acc[rtl][2 + t], vu = acc[rtl][4 + t],
            v0 = acc[rtl][6 + t], v1 = acc[rtl][8 + t];
      const int ib = i0 + wry * 64 + rtl * 16 + node_c * 4;
      #pragma unroll
      for (int r = 0; r < 4; ++r) {
        int i = ib + r;
        int tok = tokens[node0 + i];
        f32x4 wp = ((const f32x4*)g_Wpack)[(size_t)tok * 512 + j];
        float ig = vi[r] + wp[0];
        float og = vo[r] + wp[1];
        float ug = vu[r] + wp[2];
        float fpre = wp[3];
        float cc = sigm(ig) * ftanh(ug)
                 + sigm(fpre + v0[r]) * cprev[(size_t)(2 * i) * 512 + j]
                 + sigm(fpre + v1[r]) * cprev[(size_t)(2 * i + 1) * 512 + j];
        float hh = sigm(og) * ftanh(cc);
        hout[(size_t)i * 512 + j] = f2bf(hh);
        cout[(size_t)i * 512 + j] = cc;
      }
    }
  }
}

// ------------- small levels (n <= 128): fused GEMV, Wpack epilogue ---------
__global__ __launch_bounds__(256) void k_small(int lvl,
    const int* __restrict__ tokens) {
  const int n = 1 << lvl;
  const int node0 = n - 1;
  const int outp = lvl & 1;
  const ushort_t* __restrict__ hprev = outp ? g_hb0 : g_hb1;
  const float* __restrict__ cprev = outp ? g_c0 : g_c1;
  ushort_t* __restrict__ hout = outp ? g_hb1 : g_hb0;
  float* __restrict__ cout = outp ? g_c1 : g_c0;

  const int i = blockIdx.y;
  const int j0 = blockIdx.x * 64;
  const int tid = threadIdx.x;
  const int g = tid >> 6;
  const int jc = tid & 63;
  const int jj = j0 + jc;

  __shared__ float hl[1024];
  __shared__ float exch[5][64];
  for (int t = tid; t < 1024; t += 256) hl[t] = bf2f(hprev[(size_t)i * 1024 + t]);
  __syncthreads();

  const ushort_t* col = (g < 3) ? (g_UiouT + (size_t)(g * 512 + jj) * 1024)
                                : (g_UfT + (size_t)jj * 1024);
  float a0 = 0.f, a1 = 0.f;
  #pragma unroll 4
  for (int k0 = 0; k0 < 512; k0 += 8) {
    s16x8 wv = *(const s16x8*)(col + k0);
    #pragma unroll
    for (int r = 0; r < 8; ++r) a0 += hl[k0 + r] * bf2f((ushort_t)wv[r]);
  }
  #pragma unroll 4
  for (int k0 = 512; k0 < 1024; k0 += 8) {
    s16x8 wv = *(const s16x8*)(col + k0);
    #pragma unroll
    for (int r = 0; r < 8; ++r) a1 += hl[k0 + r] * bf2f((ushort_t)wv[r]);
  }
  if (g < 3) exch[g][jc] = a0 + a1;
  else { exch[3][jc] = a0; exch[4][jc] = a1; }
  __syncthreads();

  if (tid < 64) {
    int j = j0 + tid;
    int tok = tokens[node0 + i];
    f32x4 wp = ((const f32x4*)g_Wpack)[(size_t)tok * 512 + j];
    float ig = exch[0][tid] + wp[0];
    float og = exch[1][tid] + wp[1];
    float ug = exch[2][tid] + wp[2];
    float fpre = wp[3];
    float cc = sigm(ig) * ftanh(ug)
             + sigm(fpre + exch[3][tid]) * cprev[(size_t)(2 * i) * 512 + j]
             + sigm(fpre + exch[4][tid]) * cprev[(size_t)(2 * i + 1) * 512 + j];
    float hh = sigm(og) * ftanh(cc);
    hout[(size_t)i * 512 + j] = f2bf(hh);
    cout[(size_t)i * 512 + j] = cc;
  }
}

// ---------------- root ternary cell: 2-phase k-split -----------------------
__global__ __launch_bounds__(256) void k_root_p1() {
  const int by = blockIdx.y;
  const int tid = threadIdx.x;
  const int c = blockIdx.x * 256 + tid;

  __shared__ float hl[512];
  {
    int m0 = by * 512;
    #pragma unroll
    for (int q = 0; q < 2; ++q) {
      int t = tid + q * 256, m = m0 + t;
      hl[t] = (m < 512) ? bf2f(g_hb0[m]) : bf2f(g_hb1[m - 512]);
    }
  }
  __syncthreads();

  float acc = 0.f;
  const ushort_t* col = nullptr;
  if (c < 1536) {
    col = g_UiouTt + (size_t)c * 1536 + by * 512;
  } else {
    int v = c - 1536;
    if ((v >> 9) == by) col = g_UfTt + (size_t)(v & 511) * 1536 + by * 512;
  }
  if (col) {
    #pragma unroll 4
    for (int k0 = 0; k0 < 512; k0 += 8) {
      s16x8 wv = *(const s16x8*)(col + k0);
      #pragma unroll
      for (int r = 0; r < 8; ++r) acc += hl[k0 + r] * bf2f((ushort_t)wv[r]);
    }
  }
  g_rpart[(size_t)by * 3072 + c] = acc;
}

// ---------------- root phase 2 + FFN head, single block --------------------
__global__ __launch_bounds__(512) void k_p2h1(const int* __restrict__ tokens,
    const float* __restrict__ Wiou_t, const float* __restrict__ biou_t,
    const float* __restrict__ Wf_t, const float* __restrict__ bf_t,
    const float* __restrict__ ffnW, const float* __restrict__ ffnb) {
  __shared__ float hroot[H];
  const int j = threadIdx.x;
  float ai = g_rpart[j] + g_rpart[3072 + j] + g_rpart[6144 + j];
  float ao = g_rpart[512 + j] + g_rpart[3072 + 512 + j] + g_rpart[6144 + 512 + j];
  float au = g_rpart[1024 + j] + g_rpart[3072 + 1024 + j] + g_rpart[6144 + 1024 + j];
  float f0 = g_rpart[1536 + j] + g_rpart[3072 + 1536 + j] + g_rpart[6144 + 1536 + j];
  float f1 = g_rpart[2048 + j] + g_rpart[3072 + 2048 + j] + g_rpart[6144 + 2048 + j];
  float f2 = g_rpart[2560 + j] + g_rpart[3072 + 2560 + j] + g_rpart[6144 + 2560 + j];

  int tok = tokens[0];
  float fpre = Wf_t[(size_t)tok * H + j] + bf_t[j];
  float ig = ai + Wiou_t[(size_t)tok * 3 * H + j] + biou_t[j];
  float og = ao + Wiou_t[(size_t)tok * 3 * H + H + j] + biou_t[H + j];
  float ug = au + Wiou_t[(size_t)tok * 3 * H + 2 * H + j] + biou_t[2 * H + j];
  float cc = sigm(ig) * ftanh(ug)
           + sigm(fpre + f0) * g_c0[j]
           + sigm(fpre + f1) * g_c1[j]
           + sigm(fpre + f2) * g_c1[H + j];
  hroot[j] = sigm(og) * ftanh(cc);
  __syncthreads();

  float acc = ffnb[j];
  #pragma unroll 8
  for (int m = 0; m < H; ++m) acc += hroot[m] * ffnW[m * H + j];
  g_hf[j] = fmaxf(acc, 0.0f);
}

// ---------------- head2: only the 1536 live gates --------------------------
__global__ __launch_bounds__(64) void k_head2(const float* __restrict__ Wx,
                                              const float* __restrict__ lb) {
  int idx = blockIdx.x * 64 + threadIdx.x;
  int region = idx >> 9;
  int j = idx & 511;
  int g2 = (region == 0) ? j : ((region == 1) ? 1024 + j : 1536 + j);
  float acc = lb[g2];
  #pragma unroll 8
  for (int m = 0; m < H; ++m) acc += g_hf[m] * Wx[m * 4 * H + g2];
  g_gates[g2] = acc;
}

__global__ __launch_bounds__(512) void k_head3(const float* __restrict__ vm,
    const float* __restrict__ hlW, const float* __restrict__ hlb,
    const float* __restrict__ intW, const float* __restrict__ intb,
    const float* __restrict__ actW, const float* __restrict__ actb,
    float* __restrict__ out) {
  __shared__ float feat[2 * H];
  int j = threadIdx.x;
  float ci = sigm(g_gates[j]) * ftanh(g_gates[2 * H + j]);
  float hg = sigm(g_gates[3 * H + j]) * ftanh(ci);
  feat[j] = g_hf[j];
  feat[H + j] = hg;
  __syncthreads();

  const int wv = threadIdx.x >> 6;
  const int lane = threadIdx.x & 63;
  for (int o = wv; o < 43; o += 8) {
    const float* Wc;
    int stride, colb;
    if (o < 2)       { Wc = hlW;  stride = 2;  colb = o; }
    else if (o < 7)  { Wc = intW; stride = 5;  colb = o - 2; }
    else             { Wc = actW; stride = 36; colb = o - 7; }
    float s = 0.f;
    #pragma unroll
    for (int q = 0; q < 16; ++q) {
      int m = lane + q * 64;
      s += feat[m] * Wc[(size_t)m * stride + colb];
    }
    #pragma unroll
    for (int d = 32; d >= 1; d >>= 1) s += __shfl_xor(s, d);
    if (lane == 0) {
      float res;
      if (o < 2)      res = s + hlb[o];
      else if (o < 7) res = s + intb[o - 2];
      else {
        int a = o - 7;
        float v = vm[a];
        res = __logf(v) + s * v + actb[a] * v;
      }
      out[o] = res;
    }
  }
}

extern "C" void kernel_launch(void* const* d_in, const int* in_sizes, int n_in,
                              void* d_out, int out_size, void* d_ws, size_t ws_size,
                              hipStream_t stream) {
  (void)in_sizes; (void)n_in; (void)d_ws; (void)ws_size; (void)out_size;
  const int* tokens   = (const int*)d_in[0];
  const float* vm     = (const float*)d_in[1];
  const float* Wiou_b = (const float*)d_in[2];
  const float* Uiou_b = (const float*)d_in[3];
  const float* biou_b = (const float*)d_in[4];
  const float* Wf_b   = (const float*)d_in[5];
  const float* Uf_b   = (const float*)d_in[6];
  const float* bf_b   = (const float*)d_in[7];
  const float* Wiou_t = (const float*)d_in[8];
  const float* Uiou_t = (const float*)d_in[9];
  const float* biou_t = (const float*)d_in[10];
  const float* Wf_t   = (const float*)d_in[11];
  const float* Uf_t   = (const float*)d_in[12];
  const float* bf_t   = (const float*)d_in[13];
  const float* ffnW   = (const float*)d_in[14];
  const float* ffnb   = (const float*)d_in[15];
  const float* lstmWx = (const float*)d_in[16];
  const float* lstmb  = (const float*)d_in[18];
  const float* hlW    = (const float*)d_in[19];
  const float* hlb    = (const float*)d_in[20];
  const float* intW   = (const float*)d_in[21];
  const float* intb   = (const float*)d_in[22];
  const float* actW   = (const float*)d_in[23];
  const float* actb   = (const float*)d_in[24];

  ushort_t* UiouT;  hipGetSymbolAddress((void**)&UiouT, HIP_SYMBOL(g_UiouT));
  ushort_t* UfT;    hipGetSymbolAddress((void**)&UfT, HIP_SYMBOL(g_UfT));
  ushort_t* UiouTt; hipGetSymbolAddress((void**)&UiouTt, HIP_SYMBOL(g_UiouTt));
  ushort_t* UfTt;   hipGetSymbolAddress((void**)&UfTt, HIP_SYMBOL(g_UfTt));

  // transposes + Wpack/leaf tables in one launch
  k_prep<<<dim3(48, 48, 5), 256, 0, stream>>>(
      Uiou_b, Uf_b, Uiou_t, Uf_t, UiouT, UfT, UiouTt, UfTt,
      Wiou_b, biou_b, Wf_b, bf_b);

  // token-level Uh tables, then lvl-13 as pure gather+elementwise
  k_uh<<<dim3(128, 16), 256, 0, stream>>>();
  k_top_cell<<<2048, 256, 0, stream>>>(tokens);

  for (int lvl = 12; lvl >= 8; --lvl) {
    int gx = (1 << lvl) / 128;
    k_mfma_rest<<<dim3(gx, 8), 256, 0, stream>>>(lvl, tokens);
  }
  for (int lvl = 7; lvl >= 0; --lvl) {
    int n = 1 << lvl;
    k_small<<<dim3(8, n), 256, 0, stream>>>(lvl, tokens);
  }
  k_root_p1<<<dim3(12, 3), 256, 0, stream>>>();
  k_p2h1<<<1, 512, 0, stream>>>(tokens, Wiou_t, biou_t, Wf_t, bf_t, ffnW, ffnb);
  k_head2<<<24, 64, 0, stream>>>(lstmWx, lstmb);
  k_head3<<<1, 512, 0, stream>>>(vm, hlW, hlb, intW, intb, actW, actb, (float*)d_out);
}